// Round 4
// baseline (242.359 us; speedup 1.0000x reference)
//
#include <hip/hip_runtime.h>

// MobileMQA: B=8, C=256, H=W=64, NUM_HEADS=4, hd=64, ds=2
// R11: remove the plds LDS round-trip in k_fused. S-output C-layout
//      (q=lane16, kv=quad*4+r) IS the B-frag layout of K=16 MFMA
//      (mfma_f32_16x16x16bf16_1k: col=lane16, k=quad*4+j), so P feeds PV
//      directly from registers after exp+pack. PV/den become K=16 MFMAs
//      with V as 8B A-frags. plds deleted (LDS 40,960->36,864B, conflicts
//      should vanish). k_xnt: XOR-swizzle chunk^( (row>>2)&7 ) on the
//      transpose tile — old writes were a 32-way bank conflict.

#define CNT_INV (1.0f/1048576.0f)
#define EPSV 1e-5f
#define QSCALE 0.18033688f   // 0.125 * log2(e): folded into Q; exp becomes v_exp_f32(S)

// workspace layout (float offsets)
#define WS_STATS 0                    // 64
#define WS_XNT   64                   // bf16 xnT [b][n][c]  = 4,194,304 f
#define WS_XDS   4194368              // bf16 xdsT [b][m][c] = 1,048,576 f
#define WS_K     5242944              // bf16 k   [b][m][d]  = 262,144 f
#define WS_V     5505088              // bf16 vT  [b][d][m]  = 262,144 f
#define WS_WQB   5767232              // bf16 wq  [o][c]     = 32,768 f
#define WS_WKV   5800000              // bf16 [wk;wv]        = 16,384 f
#define WS_WOB   5816384              // bf16 wo  [o][c]     = 32,768 f

typedef __attribute__((ext_vector_type(8))) short bf8_t;   // 8 bf16 MFMA A/B frag (K=32)
typedef __attribute__((ext_vector_type(4))) short bf4_t;   // 4 bf16 MFMA A/B frag (K=16)
typedef __attribute__((ext_vector_type(4))) float f4_t;    // MFMA C/D frag

static __device__ __forceinline__ unsigned fbits(float f) {
  union { float f; unsigned u; } v; v.f = f; return v.u;
}
static __device__ __forceinline__ unsigned short f2bf(float f) {  // RNE
  unsigned u = fbits(f);
  return (unsigned short)((u + 0x7fffu + ((u >> 16) & 1u)) >> 16);
}
static __device__ __forceinline__ unsigned pk_rnd(float a, float b) {
  return __builtin_amdgcn_perm(fbits(b) + 0x8000u, fbits(a) + 0x8000u, 0x07060302u);
}
static __device__ __forceinline__ unsigned pk_tr(float a, float b) {
  return __builtin_amdgcn_perm(fbits(b), fbits(a), 0x07060302u);
}
static __device__ __forceinline__ float bf2f(unsigned short h) {
  union { unsigned u; float f; } v; v.u = ((unsigned)h) << 16; return v.f;
}
static __device__ __forceinline__ float fexp2(float x) {   // 2^x, raw v_exp_f32
  float r; asm("v_exp_f32 %0, %1" : "=v"(r) : "v"(x)); return r;
}
static __device__ __forceinline__ bf4_t pk2(float a, float b, float c, float d) {
  union { unsigned u[2]; bf4_t v; } pu;
  pu.u[0] = pk_tr(a, b);
  pu.u[1] = pk_tr(c, d);
  return pu.v;
}

// ---------------- merged: weight prep (blocks >= 512) + stats (blocks < 512) ----------------
__global__ __launch_bounds__(256) void k_prep_stats(const float* __restrict__ x,
                                                    const float* __restrict__ wq,
                                                    const float* __restrict__ wk,
                                                    const float* __restrict__ wv,
                                                    const float* __restrict__ wo,
                                                    float* __restrict__ stats,
                                                    unsigned short* __restrict__ wqb,
                                                    unsigned short* __restrict__ wkvb,
                                                    unsigned short* __restrict__ wob) {
  const int blk = blockIdx.x;
  const int t = threadIdx.x;
  if (blk < 512) {
    const int b = blk >> 6;
    const int chunk = blk & 63;
    const float4* xb = (const float4*)(x + (size_t)b * 1048576 + (size_t)chunk * 16384);
    float s = 0.f, s2 = 0.f;
#pragma unroll
    for (int it = 0; it < 16; ++it) {
      float4 v = xb[it * 256 + t];
      s  += v.x + v.y + v.z + v.w;
      s2 += v.x * v.x + v.y * v.y + v.z * v.z + v.w * v.w;
    }
#pragma unroll
    for (int o = 32; o > 0; o >>= 1) {
      s  += __shfl_down(s, o);
      s2 += __shfl_down(s2, o);
    }
    __shared__ float red[8];
    const int wid = t >> 6;
    if ((t & 63) == 0) { red[wid] = s; red[4 + wid] = s2; }
    __syncthreads();
    if (t == 0) {
      atomicAdd(&stats[b * 2 + 0], red[0] + red[1] + red[2] + red[3]);
      atomicAdd(&stats[b * 2 + 1], red[4] + red[5] + red[6] + red[7]);
    }
  } else {
    const int idx = (blk - 512) * 256 + t;
    if (idx < 65536) wqb[idx] = f2bf(wq[idx]);
    else if (idx < 81920) wkvb[idx - 65536] = f2bf(wk[idx - 65536]);
    else if (idx < 98304) wkvb[idx - 65536] = f2bf(wv[idx - 81920]);
    else if (idx < 163840) wob[idx - 98304] = f2bf(wo[idx - 98304]);
  }
}

// ---------------- normalize + transpose + fused 2x2 pool ----------------
// LDS tile XOR-swizzled: physical 8-u16 chunk = logical chunk ^ ((row>>2)&7).
// Un-swizzled layout had all 64 lanes of the transpose-write on 2 banks (32-way).
__global__ __launch_bounds__(256) void k_xnt(const float* __restrict__ x,
                                             const float* __restrict__ gnw,
                                             const float* __restrict__ gnb,
                                             const float* __restrict__ stats,
                                             unsigned short* __restrict__ xnT,
                                             unsigned short* __restrict__ xdsT) {
  __shared__ unsigned short T[128][72];   // [n_local][c_local], chunk-swizzled
  const int t = threadIdx.x;
  const int b = blockIdx.z, c0 = blockIdx.y * 64, hp = blockIdx.x;
  const int n0 = hp * 128;
  const float mu = stats[b * 2 + 0] * CNT_INV;
  const float rstd = rsqrtf(stats[b * 2 + 1] * CNT_INV - mu * mu + EPSV);
  const int n4 = (t & 31) * 4, cl = t >> 5;
  const int wswz = t & 7;                 // (row>>2)&7 for rows n4..n4+3
#pragma unroll
  for (int p = 0; p < 8; ++p) {
    const int c = c0 + p * 8 + cl;
    const float gw = gnw[c] * rstd;
    const float gb = gnb[c] - mu * rstd * gnw[c];
    const int pc = (p ^ wswz) * 8 + cl;
    float4 v = *(const float4*)&x[(size_t)(b * 256 + c) * 4096 + n0 + n4];
    T[n4 + 0][pc] = f2bf(v.x * gw + gb);
    T[n4 + 1][pc] = f2bf(v.y * gw + gb);
    T[n4 + 2][pc] = f2bf(v.z * gw + gb);
    T[n4 + 3][pc] = f2bf(v.w * gw + gb);
  }
  __syncthreads();
  {  // write xnT: 128 rows x 64 c
    const int r = t >> 1, cb4 = (t & 1) * 4;
    const int rswz = (t >> 3) & 7;        // (r>>2)&7
    unsigned short* dst = xnT + ((size_t)b * 4096 + n0 + r) * 256 + c0 + cb4 * 8;
#pragma unroll
    for (int u = 0; u < 4; ++u)
      *(uint4*)(dst + u * 8) = *(const uint4*)&T[r][((cb4 + u) ^ rswz) * 8];
  }
  {  // fused pool: 32 m x 64 c — m-row-major thread map for coalesced store
    const int wd = t >> 3, c8 = t & 7;
    const int pswz = (wd >> 1) & 7;       // (row>>2)&7, same for all 4 source rows
    const int pc = (c8 ^ pswz) * 8;
    uint4 u0 = *(const uint4*)&T[2 * wd][pc];
    uint4 u1 = *(const uint4*)&T[2 * wd + 1][pc];
    uint4 u2 = *(const uint4*)&T[64 + 2 * wd][pc];
    uint4 u3 = *(const uint4*)&T[64 + 2 * wd + 1][pc];
    const unsigned* p0 = (const unsigned*)&u0; const unsigned* p1 = (const unsigned*)&u1;
    const unsigned* p2 = (const unsigned*)&u2; const unsigned* p3 = (const unsigned*)&u3;
    unsigned outp[4];
#pragma unroll
    for (int i = 0; i < 4; ++i) {
      float lo = (bf2f((unsigned short)p0[i]) + bf2f((unsigned short)p1[i]) +
                  bf2f((unsigned short)p2[i]) + bf2f((unsigned short)p3[i])) * 0.25f;
      float hi = (bf2f((unsigned short)(p0[i] >> 16)) + bf2f((unsigned short)(p1[i] >> 16)) +
                  bf2f((unsigned short)(p2[i] >> 16)) + bf2f((unsigned short)(p3[i] >> 16))) * 0.25f;
      outp[i] = pk_rnd(lo, hi);
    }
    *(uint4*)(xdsT + ((size_t)b * 1024 + hp * 32 + wd) * 256 + c0 + c8 * 8) = *(uint4*)outp;
  }
}

// ---------------- K/V gemm (MFMA): k[b][m][d], vT[b][d][m] bf16, LDS-staged stores ----------------
__global__ __launch_bounds__(256) void k_gemm_kv(const unsigned short* __restrict__ wkvb,
                                                 const unsigned short* __restrict__ xdsT,
                                                 unsigned short* __restrict__ kbf,
                                                 unsigned short* __restrict__ vtbf) {
  __shared__ __align__(16) unsigned short kv[2][64][72];   // [0]=K [m][d], [1]=V [d][m]
  const int t = threadIdx.x;
  const int w = t >> 6, l = t & 63, lane16 = l & 15, quad = l >> 4;
  const int m0 = blockIdx.x * 64, b = blockIdx.y;
  const unsigned short* Abase = wkvb + (size_t)(w * 32 + lane16) * 256 + quad * 8;
  const unsigned short* Bbase = xdsT + ((size_t)b * 1024 + m0 + lane16) * 256 + quad * 8;
  f4_t acc[2][4];
#pragma unroll
  for (int i = 0; i < 2; ++i)
#pragma unroll
    for (int j = 0; j < 4; ++j) acc[i][j] = (f4_t){0.f, 0.f, 0.f, 0.f};
  bf8_t Ac[2], Bc[4];
#pragma unroll
  for (int og = 0; og < 2; ++og) Ac[og] = *(const bf8_t*)(Abase + (size_t)og * 16 * 256);
#pragma unroll
  for (int mg = 0; mg < 4; ++mg) Bc[mg] = *(const bf8_t*)(Bbase + (size_t)mg * 16 * 256);
  for (int kc = 0; kc < 256; kc += 32) {
    const int kn = (kc + 32) & 255;
    bf8_t An[2], Bn[4];
#pragma unroll
    for (int og = 0; og < 2; ++og) An[og] = *(const bf8_t*)(Abase + (size_t)og * 16 * 256 + kn);
#pragma unroll
    for (int mg = 0; mg < 4; ++mg) Bn[mg] = *(const bf8_t*)(Bbase + (size_t)mg * 16 * 256 + kn);
#pragma unroll
    for (int og = 0; og < 2; ++og)
#pragma unroll
      for (int mg = 0; mg < 4; ++mg)
        acc[og][mg] = __builtin_amdgcn_mfma_f32_16x16x32_bf16(Ac[og], Bc[mg], acc[og][mg], 0, 0, 0);
#pragma unroll
    for (int og = 0; og < 2; ++og) Ac[og] = An[og];
#pragma unroll
    for (int mg = 0; mg < 4; ++mg) Bc[mg] = Bn[mg];
  }
  if (w < 2) {  // K tile -> LDS [m][d]
#pragma unroll
    for (int og = 0; og < 2; ++og)
#pragma unroll
      for (int mg = 0; mg < 4; ++mg) {
        uint2 p;
        p.x = pk_rnd(acc[og][mg][0], acc[og][mg][1]);
        p.y = pk_rnd(acc[og][mg][2], acc[og][mg][3]);
        *(uint2*)&kv[0][mg * 16 + lane16][w * 32 + og * 16 + quad * 4] = p;
      }
  } else {  // V tile -> LDS [d][m]
#pragma unroll
    for (int og = 0; og < 2; ++og)
#pragma unroll
      for (int mg = 0; mg < 4; ++mg) {
        const int d0 = (w - 2) * 32 + og * 16 + quad * 4;
#pragma unroll
        for (int r = 0; r < 4; ++r)
          kv[1][d0 + r][mg * 16 + lane16] = f2bf(acc[og][mg][r]);
      }
  }
  __syncthreads();
  {  // coalesced writeout: row = 64 u16 = 8 uint4; thread t -> (row t>>2, 2x uint4)
    const int row = t >> 2, seg = (t & 3) * 16;
    uint4 k0 = *(const uint4*)&kv[0][row][seg];
    uint4 k1 = *(const uint4*)&kv[0][row][seg + 8];
    unsigned short* kd = kbf + (size_t)b * 65536 + (size_t)(m0 + row) * 64 + seg;
    *(uint4*)kd = k0; *(uint4*)(kd + 8) = k1;
    uint4 v0 = *(const uint4*)&kv[1][row][seg];
    uint4 v1 = *(const uint4*)&kv[1][row][seg + 8];
    unsigned short* vd = vtbf + (size_t)b * 65536 + (size_t)row * 1024 + m0 + seg;
    *(uint4*)vd = v0; *(uint4*)(vd + 8) = v1;
  }
}

// ---------------- fused Q-proj + attention + WO + residual ----------------
// block = (b, 64-n tile), wave = head. LDS phases unioned (36,864 B):
//   qst  [4][64][72] u16 (36,864 B)  — Q restage, per wave
//   aos  [64][264] u16 (33,792 B)    — block-shared ao tile
// Phase 2 uses NO LDS: P goes S-regs -> exp -> pack -> K=16 PV directly
// (C-layout == B-frag layout of mfma_f32_16x16x16bf16_1k).
__global__ __launch_bounds__(256) void k_fused(const unsigned short* __restrict__ wqb,
                                               const unsigned short* __restrict__ xnT,
                                               const unsigned short* __restrict__ kbf,
                                               const unsigned short* __restrict__ vtbf,
                                               const unsigned short* __restrict__ wob,
                                               const float* __restrict__ x,
                                               const float* __restrict__ gamma,
                                               float* __restrict__ outp) {
  __shared__ __align__(16) unsigned short smem[18432];   // 36,864 B
  const int t = threadIdx.x;
  const int w = t >> 6, l = t & 63, lane16 = l & 15, quad = l >> 4;
  const int n0 = blockIdx.x * 64, b = blockIdx.y;
  const int h = w;
  unsigned short* qst = smem + w * 4608;                               // [64][72]
  unsigned short (*aos)[264] = (unsigned short (*)[264])smem;

  const unsigned short* kb = kbf + (size_t)b * 65536;
  const unsigned short* vb = vtbf + (size_t)b * 65536;

  // ---- Phase 1: Q-proj 64q x 64d for this head, restage via LDS ----
  {
    const unsigned short* Abase = wqb + (size_t)(h * 64 + lane16) * 256 + quad * 8;
    const unsigned short* Bbase = xnT + ((size_t)b * 4096 + n0 + lane16) * 256 + quad * 8;
    f4_t qacc[4][4];
#pragma unroll
    for (int i = 0; i < 4; ++i)
#pragma unroll
      for (int j = 0; j < 4; ++j) qacc[i][j] = (f4_t){0.f, 0.f, 0.f, 0.f};
    for (int kc = 0; kc < 256; kc += 32) {
      bf8_t A[4], Bf[4];
#pragma unroll
      for (int og = 0; og < 4; ++og) A[og] = *(const bf8_t*)(Abase + (size_t)og * 16 * 256 + kc);
#pragma unroll
      for (int ng = 0; ng < 4; ++ng) Bf[ng] = *(const bf8_t*)(Bbase + (size_t)ng * 16 * 256 + kc);
#pragma unroll
      for (int og = 0; og < 4; ++og)
#pragma unroll
        for (int ng = 0; ng < 4; ++ng)
          qacc[og][ng] = __builtin_amdgcn_mfma_f32_16x16x32_bf16(A[og], Bf[ng], qacc[og][ng], 0, 0, 0);
    }
    // C-layout (row d = og*16+quad*4+r, col q = ng*16+lane16) -> qst[q][d]
#pragma unroll
    for (int og = 0; og < 4; ++og)
#pragma unroll
      for (int ng = 0; ng < 4; ++ng) {
        uint2 p;
        p.x = pk_rnd(qacc[og][ng][0] * QSCALE, qacc[og][ng][1] * QSCALE);
        p.y = pk_rnd(qacc[og][ng][2] * QSCALE, qacc[og][ng][3] * QSCALE);
        *(uint2*)&qst[(ng * 16 + lane16) * 72 + og * 16 + quad * 4] = p;
      }
  }
  bf8_t Qf[4][2];
#pragma unroll
  for (int qg = 0; qg < 4; ++qg)
#pragma unroll
    for (int dc = 0; dc < 2; ++dc)
      Qf[qg][dc] = *(const bf8_t*)&qst[(qg * 16 + lane16) * 72 + dc * 32 + quad * 8];
  __syncthreads();   // all waves' qst reads done before aos may overwrite

  // ---- Phase 2: attention, P entirely in registers (K=16 PV) ----
  f4_t O[4][4];
#pragma unroll
  for (int dg = 0; dg < 4; ++dg)
#pragma unroll
    for (int qg = 0; qg < 4; ++qg) O[dg][qg] = (f4_t){0.f, 0.f, 0.f, 0.f};
  f4_t O4[4];
#pragma unroll
  for (int qg = 0; qg < 4; ++qg) O4[qg] = (f4_t){0.f, 0.f, 0.f, 0.f};
  // ones-row A frag (K=16): row 0 (lane16==0) holds 1.0; D row0 = sum_m P = den
  const short onebf = (lane16 == 0) ? (short)0x3F80 : (short)0;
  const bf4_t Aone = {onebf, onebf, onebf, onebf};

  bf8_t Kc[2][2];
  bf4_t Va[4][2];
#pragma unroll
  for (int s = 0; s < 2; ++s)
#pragma unroll
    for (int dc = 0; dc < 2; ++dc)
      Kc[s][dc] = *(const bf8_t*)(kb + (size_t)(s * 16 + lane16) * 64 + dc * 32 + quad * 8);
#pragma unroll
  for (int dg = 0; dg < 4; ++dg)
#pragma unroll
    for (int s = 0; s < 2; ++s)
      Va[dg][s] = *(const bf4_t*)(vb + (size_t)(dg * 16 + lane16) * 1024 + s * 16 + quad * 4);

  for (int it = 0; it < 32; ++it) {
    // prefetch next KV step
    const int kvn = ((it + 1) & 31) * 32;
    bf8_t K2[2][2];
    bf4_t V2[4][2];
#pragma unroll
    for (int s = 0; s < 2; ++s)
#pragma unroll
      for (int dc = 0; dc < 2; ++dc)
        K2[s][dc] = *(const bf8_t*)(kb + (size_t)(kvn + s * 16 + lane16) * 64 + dc * 32 + quad * 8);
#pragma unroll
    for (int dg = 0; dg < 4; ++dg)
#pragma unroll
      for (int s = 0; s < 2; ++s)
        V2[dg][s] = *(const bf4_t*)(vb + (size_t)(dg * 16 + lane16) * 1024 + kvn + s * 16 + quad * 4);

#pragma unroll
    for (int qg = 0; qg < 4; ++qg) {
      f4_t S0 = (f4_t){0.f, 0.f, 0.f, 0.f};
      f4_t S1 = (f4_t){0.f, 0.f, 0.f, 0.f};
      S0 = __builtin_amdgcn_mfma_f32_16x16x32_bf16(Kc[0][0], Qf[qg][0], S0, 0, 0, 0);
      S0 = __builtin_amdgcn_mfma_f32_16x16x32_bf16(Kc[0][1], Qf[qg][1], S0, 0, 0, 0);
      S1 = __builtin_amdgcn_mfma_f32_16x16x32_bf16(Kc[1][0], Qf[qg][0], S1, 0, 0, 0);
      S1 = __builtin_amdgcn_mfma_f32_16x16x32_bf16(Kc[1][1], Qf[qg][1], S1, 0, 0, 0);
      // P (C-layout: q=lane16, kv=quad*4+j) == B-frag of 16x16x16 MFMA
      bf4_t P0 = pk2(fexp2(S0[0]), fexp2(S0[1]), fexp2(S0[2]), fexp2(S0[3]));
      bf4_t P1 = pk2(fexp2(S1[0]), fexp2(S1[1]), fexp2(S1[2]), fexp2(S1[3]));
      __builtin_amdgcn_s_setprio(1);
#pragma unroll
      for (int dg = 0; dg < 4; ++dg) {
        O[dg][qg] = __builtin_amdgcn_mfma_f32_16x16x16bf16_1k(Va[dg][0], P0, O[dg][qg], 0, 0, 0);
        O[dg][qg] = __builtin_amdgcn_mfma_f32_16x16x16bf16_1k(Va[dg][1], P1, O[dg][qg], 0, 0, 0);
      }
      O4[qg] = __builtin_amdgcn_mfma_f32_16x16x16bf16_1k(Aone, P0, O4[qg], 0, 0, 0);
      O4[qg] = __builtin_amdgcn_mfma_f32_16x16x16bf16_1k(Aone, P1, O4[qg], 0, 0, 0);
      __builtin_amdgcn_s_setprio(0);
    }
#pragma unroll
    for (int s = 0; s < 2; ++s)
#pragma unroll
      for (int dc = 0; dc < 2; ++dc) Kc[s][dc] = K2[s][dc];
#pragma unroll
    for (int dg = 0; dg < 4; ++dg)
#pragma unroll
      for (int s = 0; s < 2; ++s) Va[dg][s] = V2[dg][s];
  }

  // den[q] sits in O4[qg][0] of lanes quad==0, col=lane16 -> broadcast via shfl
  float rden[4];
#pragma unroll
  for (int qg = 0; qg < 4; ++qg) {
    float d = __shfl(O4[qg][0], lane16);
    rden[qg] = 1.f / d;
  }

  // ---- write ao tile: rows n, cols c = h*64 + d ----
#pragma unroll
  for (int dg = 0; dg < 4; ++dg)
#pragma unroll
    for (int qg = 0; qg < 4; ++qg) {
      const int c0 = h * 64 + dg * 16 + quad * 4;
      uint2 p;
      p.x = pk_rnd(O[dg][qg][0] * rden[qg], O[dg][qg][1] * rden[qg]);
      p.y = pk_rnd(O[dg][qg][2] * rden[qg], O[dg][qg][3] * rden[qg]);
      *(uint2*)&aos[qg * 16 + lane16][c0] = p;
    }
  __syncthreads();

  // ---- Phase 3: WO gemm from LDS + residual ----
  {
    const unsigned short* Wbase = wob + (size_t)(w * 64 + lane16) * 256 + quad * 8;
    f4_t acc[4][4];
#pragma unroll
    for (int i = 0; i < 4; ++i)
#pragma unroll
      for (int j = 0; j < 4; ++j) acc[i][j] = (f4_t){0.f, 0.f, 0.f, 0.f};
    for (int kc = 0; kc < 256; kc += 32) {
      bf8_t A[4], Bf[4];
#pragma unroll
      for (int og = 0; og < 4; ++og) A[og] = *(const bf8_t*)(Wbase + (size_t)og * 16 * 256 + kc);
#pragma unroll
      for (int ng = 0; ng < 4; ++ng) Bf[ng] = *(const bf8_t*)&aos[ng * 16 + lane16][kc + quad * 8];
#pragma unroll
      for (int og = 0; og < 4; ++og)
#pragma unroll
        for (int ng = 0; ng < 4; ++ng)
          acc[og][ng] = __builtin_amdgcn_mfma_f32_16x16x32_bf16(A[og], Bf[ng], acc[og][ng], 0, 0, 0);
    }
#pragma unroll
    for (int og = 0; og < 4; ++og) {
      float4 g4 = *(const float4*)&gamma[w * 64 + og * 16 + quad * 4];
      const float g[4] = {g4.x, g4.y, g4.z, g4.w};
#pragma unroll
      for (int ng = 0; ng < 4; ++ng) {
        const int n = n0 + ng * 16 + lane16;
#pragma unroll
        for (int r = 0; r < 4; ++r) {
          const int o = w * 64 + og * 16 + quad * 4 + r;
          const size_t ix = ((size_t)(b * 256 + o)) * 4096 + n;
          outp[ix] = x[ix] + g[r] * acc[og][ng][r];
        }
      }
    }
  }
}

extern "C" void kernel_launch(void* const* d_in, const int* in_sizes, int n_in,
                              void* d_out, int out_size, void* d_ws, size_t ws_size,
                              hipStream_t stream) {
  const float* x     = (const float*)d_in[0];
  const float* gnw   = (const float*)d_in[1];
  const float* gnb   = (const float*)d_in[2];
  const float* wq    = (const float*)d_in[3];
  const float* wk    = (const float*)d_in[4];
  const float* wv    = (const float*)d_in[5];
  const float* wo    = (const float*)d_in[6];
  const float* gamma = (const float*)d_in[7];
  float* out = (float*)d_out;
  float* ws  = (float*)d_ws;
  unsigned short* xnT  = (unsigned short*)(ws + WS_XNT);
  unsigned short* xdsT = (unsigned short*)(ws + WS_XDS);
  unsigned short* kbf  = (unsigned short*)(ws + WS_K);
  unsigned short* vtbf = (unsigned short*)(ws + WS_V);
  unsigned short* wqb  = (unsigned short*)(ws + WS_WQB);
  unsigned short* wkvb = (unsigned short*)(ws + WS_WKV);
  unsigned short* wob  = (unsigned short*)(ws + WS_WOB);

  hipMemsetAsync(ws, 0, 256, stream);
  k_prep_stats<<<1152, 256, 0, stream>>>(x, wq, wk, wv, wo, ws + WS_STATS, wqb, wkvb, wob);
  k_xnt<<<dim3(32, 4, 8), 256, 0, stream>>>(x, gnw, gnb, ws + WS_STATS, xnT, xdsT);
  k_gemm_kv<<<dim3(16, 8), 256, 0, stream>>>(wkvb, xdsT, kbf, vtbf);
  k_fused<<<dim3(64, 8), 256, 0, stream>>>(wqb, xnT, kbf, vtbf, wob, x, gamma, out);
}

// Round 5
// 194.060 us; speedup vs baseline: 1.2489x; 1.2489x over previous
//
#include <hip/hip_runtime.h>

// MobileMQA: B=8, C=256, H=W=64, NUM_HEADS=4, hd=64, ds=2
// R12: R10 MFMA/plds schedule kept; K/V now staged once per block into
//      double-buffered LDS (kst/vst, 4KB each x2) from window-contiguous
//      global layouts written by k_gemm_kv:
//        kbf: [b][m][d] with 16B d-chunk XOR-swizzled by (m&7)  (T2 pre-swz)
//        vtbf: [b][win32][d64][m32] contiguous 4KB windows
//      Each wave copies a coalesced 2KB slice (issue-early/write-late, T14),
//      one barrier per KV step. Frag reads = conflict-free ds_read_b128.
//      This removes the per-wave scattered global K/V gathers (4x traffic cut)
//      that R10's counters implicate as the ~50% dual-pipe stall.

#define CNT_INV (1.0f/1048576.0f)
#define EPSV 1e-5f
#define QSCALE 0.18033688f   // 0.125 * log2(e): folded into Q; exp becomes v_exp_f32(S)

// workspace layout (float offsets)
#define WS_STATS 0                    // 64
#define WS_XNT   64                   // bf16 xnT [b][n][c]  = 4,194,304 f
#define WS_XDS   4194368              // bf16 xdsT [b][m][c] = 1,048,576 f
#define WS_K     5242944              // bf16 k   [b][m][d]  = 262,144 f
#define WS_V     5505088              // bf16 v windows      = 262,144 f
#define WS_WQB   5767232              // bf16 wq  [o][c]     = 32,768 f
#define WS_WKV   5800000              // bf16 [wk;wv]        = 16,384 f
#define WS_WOB   5816384              // bf16 wo  [o][c]     = 32,768 f

typedef __attribute__((ext_vector_type(8))) short bf8_t;   // 8 bf16 MFMA A/B frag
typedef __attribute__((ext_vector_type(4))) float f4_t;    // MFMA C/D frag

static __device__ __forceinline__ unsigned fbits(float f) {
  union { float f; unsigned u; } v; v.f = f; return v.u;
}
static __device__ __forceinline__ unsigned short f2bf(float f) {  // RNE
  unsigned u = fbits(f);
  return (unsigned short)((u + 0x7fffu + ((u >> 16) & 1u)) >> 16);
}
static __device__ __forceinline__ unsigned pk_rnd(float a, float b) {
  return __builtin_amdgcn_perm(fbits(b) + 0x8000u, fbits(a) + 0x8000u, 0x07060302u);
}
static __device__ __forceinline__ unsigned pk_tr(float a, float b) {
  return __builtin_amdgcn_perm(fbits(b), fbits(a), 0x07060302u);
}
static __device__ __forceinline__ float bf2f(unsigned short h) {
  union { unsigned u; float f; } v; v.u = ((unsigned)h) << 16; return v.f;
}
static __device__ __forceinline__ float fexp2(float x) {   // 2^x, raw v_exp_f32
  float r; asm("v_exp_f32 %0, %1" : "=v"(r) : "v"(x)); return r;
}

// ---------------- merged: weight prep (blocks >= 512) + stats (blocks < 512) ----------------
__global__ __launch_bounds__(256) void k_prep_stats(const float* __restrict__ x,
                                                    const float* __restrict__ wq,
                                                    const float* __restrict__ wk,
                                                    const float* __restrict__ wv,
                                                    const float* __restrict__ wo,
                                                    float* __restrict__ stats,
                                                    unsigned short* __restrict__ wqb,
                                                    unsigned short* __restrict__ wkvb,
                                                    unsigned short* __restrict__ wob) {
  const int blk = blockIdx.x;
  const int t = threadIdx.x;
  if (blk < 512) {
    const int b = blk >> 6;
    const int chunk = blk & 63;
    const float4* xb = (const float4*)(x + (size_t)b * 1048576 + (size_t)chunk * 16384);
    float s = 0.f, s2 = 0.f;
#pragma unroll
    for (int it = 0; it < 16; ++it) {
      float4 v = xb[it * 256 + t];
      s  += v.x + v.y + v.z + v.w;
      s2 += v.x * v.x + v.y * v.y + v.z * v.z + v.w * v.w;
    }
#pragma unroll
    for (int o = 32; o > 0; o >>= 1) {
      s  += __shfl_down(s, o);
      s2 += __shfl_down(s2, o);
    }
    __shared__ float red[8];
    const int wid = t >> 6;
    if ((t & 63) == 0) { red[wid] = s; red[4 + wid] = s2; }
    __syncthreads();
    if (t == 0) {
      atomicAdd(&stats[b * 2 + 0], red[0] + red[1] + red[2] + red[3]);
      atomicAdd(&stats[b * 2 + 1], red[4] + red[5] + red[6] + red[7]);
    }
  } else {
    const int idx = (blk - 512) * 256 + t;
    if (idx < 65536) wqb[idx] = f2bf(wq[idx]);
    else if (idx < 81920) wkvb[idx - 65536] = f2bf(wk[idx - 65536]);
    else if (idx < 98304) wkvb[idx - 65536] = f2bf(wv[idx - 81920]);
    else if (idx < 163840) wob[idx - 98304] = f2bf(wo[idx - 98304]);
  }
}

// ---------------- normalize + transpose + fused 2x2 pool ----------------
// LDS tile XOR-swizzled: physical 8-u16 chunk = logical chunk ^ ((row>>2)&7).
__global__ __launch_bounds__(256) void k_xnt(const float* __restrict__ x,
                                             const float* __restrict__ gnw,
                                             const float* __restrict__ gnb,
                                             const float* __restrict__ stats,
                                             unsigned short* __restrict__ xnT,
                                             unsigned short* __restrict__ xdsT) {
  __shared__ unsigned short T[128][72];   // [n_local][c_local], chunk-swizzled
  const int t = threadIdx.x;
  const int b = blockIdx.z, c0 = blockIdx.y * 64, hp = blockIdx.x;
  const int n0 = hp * 128;
  const float mu = stats[b * 2 + 0] * CNT_INV;
  const float rstd = rsqrtf(stats[b * 2 + 1] * CNT_INV - mu * mu + EPSV);
  const int n4 = (t & 31) * 4, cl = t >> 5;
  const int wswz = t & 7;                 // (row>>2)&7 for rows n4..n4+3
#pragma unroll
  for (int p = 0; p < 8; ++p) {
    const int c = c0 + p * 8 + cl;
    const float gw = gnw[c] * rstd;
    const float gb = gnb[c] - mu * rstd * gnw[c];
    const int pc = (p ^ wswz) * 8 + cl;
    float4 v = *(const float4*)&x[(size_t)(b * 256 + c) * 4096 + n0 + n4];
    T[n4 + 0][pc] = f2bf(v.x * gw + gb);
    T[n4 + 1][pc] = f2bf(v.y * gw + gb);
    T[n4 + 2][pc] = f2bf(v.z * gw + gb);
    T[n4 + 3][pc] = f2bf(v.w * gw + gb);
  }
  __syncthreads();
  {  // write xnT: 128 rows x 64 c
    const int r = t >> 1, cb4 = (t & 1) * 4;
    const int rswz = (t >> 3) & 7;        // (r>>2)&7
    unsigned short* dst = xnT + ((size_t)b * 4096 + n0 + r) * 256 + c0 + cb4 * 8;
#pragma unroll
    for (int u = 0; u < 4; ++u)
      *(uint4*)(dst + u * 8) = *(const uint4*)&T[r][((cb4 + u) ^ rswz) * 8];
  }
  {  // fused pool: 32 m x 64 c — m-row-major thread map for coalesced store
    const int wd = t >> 3, c8 = t & 7;
    const int pswz = (wd >> 1) & 7;       // (row>>2)&7, same for all 4 source rows
    const int pc = (c8 ^ pswz) * 8;
    uint4 u0 = *(const uint4*)&T[2 * wd][pc];
    uint4 u1 = *(const uint4*)&T[2 * wd + 1][pc];
    uint4 u2 = *(const uint4*)&T[64 + 2 * wd][pc];
    uint4 u3 = *(const uint4*)&T[64 + 2 * wd + 1][pc];
    const unsigned* p0 = (const unsigned*)&u0; const unsigned* p1 = (const unsigned*)&u1;
    const unsigned* p2 = (const unsigned*)&u2; const unsigned* p3 = (const unsigned*)&u3;
    unsigned outp[4];
#pragma unroll
    for (int i = 0; i < 4; ++i) {
      float lo = (bf2f((unsigned short)p0[i]) + bf2f((unsigned short)p1[i]) +
                  bf2f((unsigned short)p2[i]) + bf2f((unsigned short)p3[i])) * 0.25f;
      float hi = (bf2f((unsigned short)(p0[i] >> 16)) + bf2f((unsigned short)(p1[i] >> 16)) +
                  bf2f((unsigned short)(p2[i] >> 16)) + bf2f((unsigned short)(p3[i] >> 16))) * 0.25f;
      outp[i] = pk_rnd(lo, hi);
    }
    *(uint4*)(xdsT + ((size_t)b * 1024 + hp * 32 + wd) * 256 + c0 + c8 * 8) = *(uint4*)outp;
  }
}

// ---------------- K/V gemm (MFMA): window-contiguous outputs for LDS staging ----------------
// kbf: [b][m][64 d], d stored as 8x 16B chunks, phys chunk = logical ^ (m&7)
// vtbf: [b][win(32)][d(64)][m(32)] — 4KB contiguous per window
__global__ __launch_bounds__(256) void k_gemm_kv(const unsigned short* __restrict__ wkvb,
                                                 const unsigned short* __restrict__ xdsT,
                                                 unsigned short* __restrict__ kbf,
                                                 unsigned short* __restrict__ vtbf) {
  __shared__ __align__(16) unsigned short kv[2][64][72];   // [0]=K [m][d], [1]=V [d][m]
  const int t = threadIdx.x;
  const int w = t >> 6, l = t & 63, lane16 = l & 15, quad = l >> 4;
  const int m0 = blockIdx.x * 64, b = blockIdx.y;
  const unsigned short* Abase = wkvb + (size_t)(w * 32 + lane16) * 256 + quad * 8;
  const unsigned short* Bbase = xdsT + ((size_t)b * 1024 + m0 + lane16) * 256 + quad * 8;
  f4_t acc[2][4];
#pragma unroll
  for (int i = 0; i < 2; ++i)
#pragma unroll
    for (int j = 0; j < 4; ++j) acc[i][j] = (f4_t){0.f, 0.f, 0.f, 0.f};
  bf8_t Ac[2], Bc[4];
#pragma unroll
  for (int og = 0; og < 2; ++og) Ac[og] = *(const bf8_t*)(Abase + (size_t)og * 16 * 256);
#pragma unroll
  for (int mg = 0; mg < 4; ++mg) Bc[mg] = *(const bf8_t*)(Bbase + (size_t)mg * 16 * 256);
  for (int kc = 0; kc < 256; kc += 32) {
    const int kn = (kc + 32) & 255;
    bf8_t An[2], Bn[4];
#pragma unroll
    for (int og = 0; og < 2; ++og) An[og] = *(const bf8_t*)(Abase + (size_t)og * 16 * 256 + kn);
#pragma unroll
    for (int mg = 0; mg < 4; ++mg) Bn[mg] = *(const bf8_t*)(Bbase + (size_t)mg * 16 * 256 + kn);
#pragma unroll
    for (int og = 0; og < 2; ++og)
#pragma unroll
      for (int mg = 0; mg < 4; ++mg)
        acc[og][mg] = __builtin_amdgcn_mfma_f32_16x16x32_bf16(Ac[og], Bc[mg], acc[og][mg], 0, 0, 0);
#pragma unroll
    for (int og = 0; og < 2; ++og) Ac[og] = An[og];
#pragma unroll
    for (int mg = 0; mg < 4; ++mg) Bc[mg] = Bn[mg];
  }
  if (w < 2) {  // K tile -> LDS [m][d]
#pragma unroll
    for (int og = 0; og < 2; ++og)
#pragma unroll
      for (int mg = 0; mg < 4; ++mg) {
        uint2 p;
        p.x = pk_rnd(acc[og][mg][0], acc[og][mg][1]);
        p.y = pk_rnd(acc[og][mg][2], acc[og][mg][3]);
        *(uint2*)&kv[0][mg * 16 + lane16][w * 32 + og * 16 + quad * 4] = p;
      }
  } else {  // V tile -> LDS [d][m]
#pragma unroll
    for (int og = 0; og < 2; ++og)
#pragma unroll
      for (int mg = 0; mg < 4; ++mg) {
        const int d0 = (w - 2) * 32 + og * 16 + quad * 4;
#pragma unroll
        for (int r = 0; r < 4; ++r)
          kv[1][d0 + r][mg * 16 + lane16] = f2bf(acc[og][mg][r]);
      }
  }
  __syncthreads();
  {  // writeout: thread t -> row t>>2, two 16B chunks
    const int row = t >> 2, q2 = t & 3;
    const int e = row & 7;
    uint4 k0 = *(const uint4*)&kv[0][row][q2 * 16];
    uint4 k1 = *(const uint4*)&kv[0][row][q2 * 16 + 8];
    unsigned short* kd = kbf + (size_t)b * 65536 + (size_t)(m0 + row) * 64;
    *(uint4*)(kd + ((q2 * 2) ^ e) * 8)     = k0;   // pre-swizzled K chunks
    *(uint4*)(kd + ((q2 * 2 + 1) ^ e) * 8) = k1;
    uint4 v0 = *(const uint4*)&kv[1][row][q2 * 16];
    uint4 v1 = *(const uint4*)&kv[1][row][q2 * 16 + 8];
    unsigned short* vd = vtbf + (size_t)b * 65536 + (size_t)(blockIdx.x * 2 + (q2 >> 1)) * 2048 +
                         (size_t)row * 32 + (q2 & 1) * 16;
    *(uint4*)vd = v0; *(uint4*)(vd + 8) = v1;      // window-contiguous V
  }
}

// ---------------- fused Q-proj + attention + WO + residual ----------------
// block = (b, 64-n tile), wave = head. LDS:
//   smem union (40,960 B): qst [4][64][72] / plds [4][2][64][40] / aos [64][264]
//   kst[2][2048] u16 (8,192 B) + vst[2][2048] u16 (8,192 B): K/V window dbuf
// Per KV step: stage next window (coalesced 2KB/wave, issue-early/write-late),
// frag-read current window from LDS (conflict-free), R10 plds P-pipeline.
__global__ __launch_bounds__(256) void k_fused(const unsigned short* __restrict__ wqb,
                                               const unsigned short* __restrict__ xnT,
                                               const unsigned short* __restrict__ kbf,
                                               const unsigned short* __restrict__ vtbf,
                                               const unsigned short* __restrict__ wob,
                                               const float* __restrict__ x,
                                               const float* __restrict__ gamma,
                                               float* __restrict__ outp) {
  __shared__ __align__(16) unsigned short smem[20480];   // 40,960 B
  __shared__ __align__(16) unsigned short kst[2][2048];  //  8,192 B
  __shared__ __align__(16) unsigned short vst[2][2048];  //  8,192 B
  const int t = threadIdx.x;
  const int w = t >> 6, l = t & 63, lane16 = l & 15, quad = l >> 4;
  const int n0 = blockIdx.x * 64, b = blockIdx.y;
  const int h = w;
  unsigned short* qst = smem + w * 4608;                               // [64][72]
  unsigned short (*plds)[64][40] = (unsigned short (*)[64][40])(smem + w * 5120);
  unsigned short (*aos)[264] = (unsigned short (*)[264])smem;

  // staging role: waves 0,1 -> K slice halves; waves 2,3 -> V slice halves
  const int sw = w & 1;
  const unsigned short* sbase = (w < 2) ? (kbf + (size_t)b * 65536) : (vtbf + (size_t)b * 65536);
  unsigned short* sdst0 = ((w < 2) ? &kst[0][0] : &vst[0][0]) + sw * 1024 + l * 8;
  unsigned short* sdst1 = ((w < 2) ? &kst[1][0] : &vst[1][0]) + sw * 1024 + l * 8;

#define STAGE_ISSUE(WIN, R0, R1)                                              \
  { const unsigned short* sp = sbase + (size_t)(WIN) * 2048 + sw * 1024 + l * 8; \
    R0 = *(const uint4*)sp; R1 = *(const uint4*)(sp + 512); }
#define STAGE_WRITE(DP, R0, R1)                                               \
  { *(uint4*)(DP) = R0; *(uint4*)((DP) + 512) = R1; }

#define READ_K(BUF, KREG)                                                     \
  {                                                                           \
    _Pragma("unroll")                                                         \
    for (int s = 0; s < 2; ++s) {                                             \
      _Pragma("unroll")                                                       \
      for (int dc = 0; dc < 2; ++dc)                                          \
        KREG[s][dc] = *(const bf8_t*)&kst[BUF][(s * 16 + lane16) * 64 +       \
                                              (((dc * 4 + quad) ^ (lane16 & 7)) * 8)]; \
    }                                                                         \
  }
#define READ_V(BUF, VREG)                                                     \
  {                                                                           \
    _Pragma("unroll")                                                         \
    for (int dg = 0; dg < 4; ++dg)                                            \
      VREG[dg] = *(const bf8_t*)&vst[BUF][(dg * 16 + lane16) * 32 + quad * 8]; \
  }

  const unsigned short* kb = kbf;  // silence unused-var style; sbase used for staging

  // ---- Phase 1: Q-proj 64q x 64d for this head, restage via LDS ----
  {
    const unsigned short* Abase = wqb + (size_t)(h * 64 + lane16) * 256 + quad * 8;
    const unsigned short* Bbase = xnT + ((size_t)b * 4096 + n0 + lane16) * 256 + quad * 8;
    f4_t qacc[4][4];
#pragma unroll
    for (int i = 0; i < 4; ++i)
#pragma unroll
      for (int j = 0; j < 4; ++j) qacc[i][j] = (f4_t){0.f, 0.f, 0.f, 0.f};
    for (int kc = 0; kc < 256; kc += 32) {
      bf8_t A[4], Bf[4];
#pragma unroll
      for (int og = 0; og < 4; ++og) A[og] = *(const bf8_t*)(Abase + (size_t)og * 16 * 256 + kc);
#pragma unroll
      for (int ng = 0; ng < 4; ++ng) Bf[ng] = *(const bf8_t*)(Bbase + (size_t)ng * 16 * 256 + kc);
#pragma unroll
      for (int og = 0; og < 4; ++og)
#pragma unroll
        for (int ng = 0; ng < 4; ++ng)
          qacc[og][ng] = __builtin_amdgcn_mfma_f32_16x16x32_bf16(A[og], Bf[ng], qacc[og][ng], 0, 0, 0);
    }
    // C-layout (row d = og*16+quad*4+r, col q = ng*16+lane16) -> qst[q][d]
#pragma unroll
    for (int og = 0; og < 4; ++og)
#pragma unroll
      for (int ng = 0; ng < 4; ++ng) {
        uint2 p;
        p.x = pk_rnd(qacc[og][ng][0] * QSCALE, qacc[og][ng][1] * QSCALE);
        p.y = pk_rnd(qacc[og][ng][2] * QSCALE, qacc[og][ng][3] * QSCALE);
        *(uint2*)&qst[(ng * 16 + lane16) * 72 + og * 16 + quad * 4] = p;
      }
  }
  bf8_t Qf[4][2];
#pragma unroll
  for (int qg = 0; qg < 4; ++qg)
#pragma unroll
    for (int dc = 0; dc < 2; ++dc)
      Qf[qg][dc] = *(const bf8_t*)&qst[(qg * 16 + lane16) * 72 + dc * 32 + quad * 8];
  __syncthreads();   // all waves read Q before plds overwrites qst space

  // ---- Phase 2: pipelined attention (PV lags S by one KV step) ----
  f4_t O[4][4];
#pragma unroll
  for (int dg = 0; dg < 4; ++dg)
#pragma unroll
    for (int qg = 0; qg < 4; ++qg) O[dg][qg] = (f4_t){0.f, 0.f, 0.f, 0.f};
  f4_t O4[4];
#pragma unroll
  for (int qg = 0; qg < 4; ++qg) O4[qg] = (f4_t){0.f, 0.f, 0.f, 0.f};
  const short onebf = (lane16 == 0) ? (short)0x3F80 : (short)0;
  const bf8_t Aone = {onebf, onebf, onebf, onebf, onebf, onebf, onebf, onebf};

#define SSTEP(KREG, BUF)                                                      \
  {                                                                           \
    _Pragma("unroll")                                                         \
    for (int qg = 0; qg < 4; ++qg) {                                          \
      _Pragma("unroll")                                                       \
      for (int s = 0; s < 2; ++s) {                                           \
        f4_t S = (f4_t){0.f, 0.f, 0.f, 0.f};                                  \
        S = __builtin_amdgcn_mfma_f32_16x16x32_bf16(KREG[s][0], Qf[qg][0], S, 0, 0, 0); \
        S = __builtin_amdgcn_mfma_f32_16x16x32_bf16(KREG[s][1], Qf[qg][1], S, 0, 0, 0); \
        float e0 = fexp2(S[0]);                                               \
        float e1 = fexp2(S[1]);                                               \
        float e2 = fexp2(S[2]);                                               \
        float e3 = fexp2(S[3]);                                               \
        uint2 p; p.x = pk_tr(e0, e1); p.y = pk_tr(e2, e3);                    \
        *(uint2*)&plds[BUF][qg * 16 + lane16][s * 16 + quad * 4] = p;         \
      }                                                                       \
    }                                                                         \
  }

  // prologue: stage windows 0 and 1
  {
    uint4 a0, a1, b0, b1;
    STAGE_ISSUE(0, a0, a1);
    STAGE_ISSUE(1, b0, b1);
    STAGE_WRITE(sdst0, a0, a1);
    STAGE_WRITE(sdst1, b0, b1);
  }
  __syncthreads();   // buf0 + buf1 ready

  bf8_t Kc[2][2], Vc[4];
  READ_K(0, Kc);
  SSTEP(Kc, 0);
  READ_V(0, Vc);
  __syncthreads();   // all waves done reading buf0 before iter1 overwrites it

  for (int it = 1; it < 32; ++it) {
    const int cur = it & 1, pb = cur ^ 1;
    uint4 g0, g1;
    if (it < 31) STAGE_ISSUE(it + 1, g0, g1);
    bf8_t Pf[4];
#pragma unroll
    for (int qg = 0; qg < 4; ++qg)
      Pf[qg] = *(const bf8_t*)&plds[pb][qg * 16 + lane16][quad * 8];
    READ_K(cur, Kc);
    bf8_t Vn[4];
    READ_V(cur, Vn);
    __builtin_amdgcn_s_setprio(1);
#pragma unroll
    for (int dg = 0; dg < 4; ++dg)
#pragma unroll
      for (int qg = 0; qg < 4; ++qg)
        O[dg][qg] = __builtin_amdgcn_mfma_f32_16x16x32_bf16(Vc[dg], Pf[qg], O[dg][qg], 0, 0, 0);
#pragma unroll
    for (int qg = 0; qg < 4; ++qg)
      O4[qg] = __builtin_amdgcn_mfma_f32_16x16x32_bf16(Aone, Pf[qg], O4[qg], 0, 0, 0);
    __builtin_amdgcn_s_setprio(0);
    SSTEP(Kc, cur);
#pragma unroll
    for (int dg = 0; dg < 4; ++dg) Vc[dg] = Vn[dg];
    if (it < 31) STAGE_WRITE((cur ? sdst0 : sdst1), g0, g1);   // write into buf pb
    __syncthreads();
  }
  {  // epilogue: PV(31), P in buf 1
    bf8_t Pf[4];
#pragma unroll
    for (int qg = 0; qg < 4; ++qg)
      Pf[qg] = *(const bf8_t*)&plds[1][qg * 16 + lane16][quad * 8];
    __builtin_amdgcn_s_setprio(1);
#pragma unroll
    for (int dg = 0; dg < 4; ++dg)
#pragma unroll
      for (int qg = 0; qg < 4; ++qg)
        O[dg][qg] = __builtin_amdgcn_mfma_f32_16x16x32_bf16(Vc[dg], Pf[qg], O[dg][qg], 0, 0, 0);
#pragma unroll
    for (int qg = 0; qg < 4; ++qg)
      O4[qg] = __builtin_amdgcn_mfma_f32_16x16x32_bf16(Aone, Pf[qg], O4[qg], 0, 0, 0);
    __builtin_amdgcn_s_setprio(0);
  }
#undef SSTEP
#undef STAGE_ISSUE
#undef STAGE_WRITE
#undef READ_K
#undef READ_V
  (void)kb;

  // den[q] sits in O4[qg][0] of lanes quad==0, col=lane16 -> broadcast via shfl
  float rden[4];
#pragma unroll
  for (int qg = 0; qg < 4; ++qg) {
    float d = __shfl(O4[qg][0], lane16);
    rden[qg] = 1.f / d;
  }

  __syncthreads();   // all waves done reading plds before aos overwrites
  // ---- write ao tile: rows n, cols c = h*64 + d ----
#pragma unroll
  for (int dg = 0; dg < 4; ++dg)
#pragma unroll
    for (int qg = 0; qg < 4; ++qg) {
      const int c0 = h * 64 + dg * 16 + quad * 4;
      uint2 p;
      p.x = pk_rnd(O[dg][qg][0] * rden[qg], O[dg][qg][1] * rden[qg]);
      p.y = pk_rnd(O[dg][qg][2] * rden[qg], O[dg][qg][3] * rden[qg]);
      *(uint2*)&aos[qg * 16 + lane16][c0] = p;
    }
  __syncthreads();

  // ---- Phase 3: WO gemm from LDS + residual ----
  {
    const unsigned short* Wbase = wob + (size_t)(w * 64 + lane16) * 256 + quad * 8;
    f4_t acc[4][4];
#pragma unroll
    for (int i = 0; i < 4; ++i)
#pragma unroll
      for (int j = 0; j < 4; ++j) acc[i][j] = (f4_t){0.f, 0.f, 0.f, 0.f};
    for (int kc = 0; kc < 256; kc += 32) {
      bf8_t A[4], Bf[4];
#pragma unroll
      for (int og = 0; og < 4; ++og) A[og] = *(const bf8_t*)(Wbase + (size_t)og * 16 * 256 + kc);
#pragma unroll
      for (int ng = 0; ng < 4; ++ng) Bf[ng] = *(const bf8_t*)&aos[ng * 16 + lane16][kc + quad * 8];
#pragma unroll
      for (int og = 0; og < 4; ++og)
#pragma unroll
        for (int ng = 0; ng < 4; ++ng)
          acc[og][ng] = __builtin_amdgcn_mfma_f32_16x16x32_bf16(A[og], Bf[ng], acc[og][ng], 0, 0, 0);
    }
#pragma unroll
    for (int og = 0; og < 4; ++og) {
      float4 g4 = *(const float4*)&gamma[w * 64 + og * 16 + quad * 4];
      const float g[4] = {g4.x, g4.y, g4.z, g4.w};
#pragma unroll
      for (int ng = 0; ng < 4; ++ng) {
        const int n = n0 + ng * 16 + lane16;
#pragma unroll
        for (int r = 0; r < 4; ++r) {
          const int o = w * 64 + og * 16 + quad * 4 + r;
          const size_t ix = ((size_t)(b * 256 + o)) * 4096 + n;
          outp[ix] = x[ix] + g[r] * acc[og][ng][r];
        }
      }
    }
  }
}

extern "C" void kernel_launch(void* const* d_in, const int* in_sizes, int n_in,
                              void* d_out, int out_size, void* d_ws, size_t ws_size,
                              hipStream_t stream) {
  const float* x     = (const float*)d_in[0];
  const float* gnw   = (const float*)d_in[1];
  const float* gnb   = (const float*)d_in[2];
  const float* wq    = (const float*)d_in[3];
  const float* wk    = (const float*)d_in[4];
  const float* wv    = (const float*)d_in[5];
  const float* wo    = (const float*)d_in[6];
  const float* gamma = (const float*)d_in[7];
  float* out = (float*)d_out;
  float* ws  = (float*)d_ws;
  unsigned short* xnT  = (unsigned short*)(ws + WS_XNT);
  unsigned short* xdsT = (unsigned short*)(ws + WS_XDS);
  unsigned short* kbf  = (unsigned short*)(ws + WS_K);
  unsigned short* vtbf = (unsigned short*)(ws + WS_V);
  unsigned short* wqb  = (unsigned short*)(ws + WS_WQB);
  unsigned short* wkvb = (unsigned short*)(ws + WS_WKV);
  unsigned short* wob  = (unsigned short*)(ws + WS_WOB);

  hipMemsetAsync(ws, 0, 256, stream);
  k_prep_stats<<<1152, 256, 0, stream>>>(x, wq, wk, wv, wo, ws + WS_STATS, wqb, wkvb, wob);
  k_xnt<<<dim3(32, 4, 8), 256, 0, stream>>>(x, gnw, gnb, ws + WS_STATS, xnT, xdsT);
  k_gemm_kv<<<dim3(16, 8), 256, 0, stream>>>(wkvb, xdsT, kbf, vtbf);
  k_fused<<<dim3(64, 8), 256, 0, stream>>>(wqb, xnT, kbf, vtbf, wob, x, gamma, out);
}